// Round 5
// baseline (22425.250 us; speedup 1.0000x reference)
//
#include <hip/hip_runtime.h>
#include <hip/hip_bf16.h>
#include <math.h>

#define B_ 64
#define T_ 1024
#define D_ 512
#define H_ 512
#define M_ 256
#define CC 63
#define SS 64
#define NBLK 512
#define INV_SQRT_2PI 0.3989422804014327f

typedef __attribute__((ext_vector_type(8))) short short8v;
typedef __attribute__((ext_vector_type(4))) float f32x4;

static __device__ __forceinline__ float bf2f(unsigned short u) {
    unsigned int x = ((unsigned int)u) << 16;
    return __uint_as_float(x);
}
static __device__ __forceinline__ unsigned short f2bf(float f) {
    unsigned int x = __float_as_uint(f);
    unsigned int r = (x + 0x7fff + ((x >> 16) & 1)) >> 16;
    return (unsigned short)r;
}
static __device__ __forceinline__ float sigm(float x) {
    return 1.f / (1.f + __expf(-x));
}
static __device__ __forceinline__ float wsum64(float v) {
    for (int o = 32; o > 0; o >>= 1) v += __shfl_xor(v, o, 64);
    return v;
}

// grid barrier: single monotone counter, agent scope (proven in rounds 2-3).
static __device__ __forceinline__ void gbar(int* bar, int& tgt) {
    tgt += NBLK;
    __syncthreads();
    if (threadIdx.x == 0) {
        __builtin_amdgcn_fence(__ATOMIC_RELEASE, "agent");
        __hip_atomic_fetch_add(bar, 1, __ATOMIC_RELAXED, __HIP_MEMORY_SCOPE_AGENT);
        while (__hip_atomic_load(bar, __ATOMIC_RELAXED, __HIP_MEMORY_SCOPE_AGENT) < tgt) {
            __builtin_amdgcn_s_sleep(4);
        }
        __builtin_amdgcn_fence(__ATOMIC_ACQUIRE, "agent");
    }
    __syncthreads();
}

// ---------------- prologue kernels ----------------

// listener f32 -> bf16 (context path only; energy path stays f32)
__global__ __launch_bounds__(256) void k_conv(const float* __restrict__ src,
        unsigned short* __restrict__ dst, int n4) {
    int stride = gridDim.x * 256;
    for (int i = blockIdx.x * 256 + threadIdx.x; i < n4; i += stride) {
        float4 v = ((const float4*)src)[i];
        ushort4 o;
        o.x = f2bf(v.x); o.y = f2bf(v.y); o.z = f2bf(v.z); o.w = f2bf(v.w);
        ((ushort4*)dst)[i] = o;
    }
}

// f32 GEMM: clT[b*256+m][t] = relu(sum_d L[b*1024+t][d]*psi[m][d] + psib[m])  (f32 out)
__global__ __launch_bounds__(256) void k_gemm(const float* __restrict__ Lf,
        const float* __restrict__ psiw, const float* __restrict__ psib,
        float* __restrict__ clT) {
    __shared__ float At[64 * 65];
    __shared__ float Bt[64 * 65];
    int tid = threadIdx.x;
    int pt = blockIdx.x >> 2;
    int mt = blockIdx.x & 3;
    int p0 = pt * 64, m0 = mt * 64;
    int tp = tid >> 4, tm = tid & 15;
    float acc[4][4] = {{0.f}};
    for (int k0 = 0; k0 < 512; k0 += 64) {
        __syncthreads();
        for (int i = 0; i < 16; ++i) {
            int lidx = i * 256 + tid;
            int r = lidx >> 6, c = lidx & 63;
            At[r * 65 + c] = Lf[(size_t)(p0 + r) * 512 + k0 + c];
            Bt[r * 65 + c] = psiw[(size_t)(m0 + r) * 512 + k0 + c];
        }
        __syncthreads();
        for (int dk = 0; dk < 64; ++dk) {
            float av[4], bv[4];
#pragma unroll
            for (int i = 0; i < 4; ++i) av[i] = At[(4 * tp + i) * 65 + dk];
#pragma unroll
            for (int j = 0; j < 4; ++j) bv[j] = Bt[(4 * tm + j) * 65 + dk];
#pragma unroll
            for (int i = 0; i < 4; ++i)
#pragma unroll
                for (int j = 0; j < 4; ++j)
                    acc[i][j] = fmaf(av[i], bv[j], acc[i][j]);
        }
    }
#pragma unroll
    for (int i = 0; i < 4; ++i) {
        int p = p0 + 4 * tp + i;
        int b = p >> 10, t = p & 1023;
#pragma unroll
        for (int j = 0; j < 4; ++j) {
            int m = m0 + 4 * tm + j;
            clT[((size_t)(b * 256 + m)) * 1024 + t] = fmaxf(acc[i][j] + psib[m], 0.f);
        }
    }
}

// ---------------- persistent mega kernel, 512 blocks ----------------

__global__ __launch_bounds__(256, 2) void k_mega(
        const float* __restrict__ Lf, const unsigned short* __restrict__ Lbf, int useBf,
        const float* __restrict__ gt,
        const float* __restrict__ phiw, const float* __restrict__ phib,
        const float* __restrict__ wih0, const float* __restrict__ whh0,
        const float* __restrict__ bih0, const float* __restrict__ bhh0,
        const float* __restrict__ wih1, const float* __restrict__ whh1,
        const float* __restrict__ bih1, const float* __restrict__ bhh1,
        const float* __restrict__ charw, const float* __restrict__ charb,
        const float* __restrict__ clT,
        float* gtT, float* h0buf, float* h1buf, float* h1bb,
        float* ctxT, float* ctxb, float* energyT, float* vbuf,
        float* cdb, float* logit, int* colZero, int* bar,
        float* preds, float* atts) {
    __shared__ float wA[8704];                 // 8 rows x 1088 (wih0|whh0|pad)
    __shared__ float wB[8192];                 // 8 rows x 1024 (wih1|whh1)
    __shared__ __align__(16) float ovl[2560];  // 10KB per-phase overlay
    __shared__ float cst[160];                 // c0[64], c1[64], biasA[8]@128, biasB[8]@136

    int tid = threadIdx.x, blk = blockIdx.x;
    int barTgt = 0;
    int rg = blk >> 1, bg = blk & 1;   // row-group (2 units), batch-half

    // ---- INIT: pinned weights, biases, state zero, gtT ----
    for (int r8i = 0; r8i < 8; ++r8i) {
        int j = (r8i >> 1) * 512 + rg * 2 + (r8i & 1);
        for (int k = tid; k < 1088; k += 256)
            wA[r8i * 1088 + k] = (k < 575) ? wih0[(size_t)j * 575 + k]
                               : (k < 1087) ? whh0[(size_t)j * 512 + (k - 575)] : 0.f;
        for (int k = tid; k < 1024; k += 256)
            wB[r8i * 1024 + k] = (k < 512) ? wih1[(size_t)j * 512 + k]
                                           : whh1[(size_t)j * 512 + (k - 512)];
    }
    if (tid < 8) {
        int j = (tid >> 1) * 512 + rg * 2 + (tid & 1);
        cst[128 + tid] = bih0[j] + bhh0[j];
        cst[136 + tid] = bih1[j] + bhh1[j];
    }
    if (tid < 128) cst[tid] = 0.f;
    if (blk < 64) {
        int s0 = blk;
        for (int r = tid; r < CC * 64; r += 256) {
            int k = r >> 6, b = r & 63;
            gtT[s0 * (CC * 64) + r] = gt[(b * SS + s0) * CC + k];
        }
    } else if (blk < 192) {
        int idx = (blk - 64) * 256 + tid;
        h0buf[idx] = 0.f;
        h1buf[idx] = 0.f;
        int d = idx >> 6, b = idx & 63;
        float v = Lf[(size_t)b * (T_ * D_) + d];
        ctxT[idx] = v;
        ctxb[b * 512 + d] = v;
    }
    gbar(bar, barTgt);

    int bl = tid & 31, r8 = tid >> 5;

    for (int s = 0; s < SS; ++s) {
        int pin = s & 1;
        const float* h0in = h0buf + pin * 32768;
        float* h0out = h0buf + (1 - pin) * 32768;
        const float* h1in = h1buf + pin * 32768;
        float* h1out = h1buf + (1 - pin) * 32768;
        const float* h1b_prev = h1bb + pin * 32768;
        float* h1b_cur = h1bb + (1 - pin) * 32768;

        // ---- phase A: LSTM0 (units rg*2+{0,1}, batch half bg) ----
        {
            float* xs = ovl;              // [32][66], stride 66: gcd(66,32)=2 -> 2-way free
            float* ex = ovl + 2112;       // [8][32]
            f32x4 a4 = {0.f, 0.f, 0.f, 0.f};
            for (int kc = 0; kc < 17; ++kc) {
                int k0 = kc * 64;
                __syncthreads();
#pragma unroll
                for (int i = 0; i < 8; ++i) {
                    int lidx = i * 256 + tid;
                    int dk = lidx >> 5, bcol = lidx & 31;
                    int k = k0 + dk;
                    int b = bg * 32 + bcol;
                    float v;
                    if (k < 63)        v = (s > 0) ? gtT[(s - 1) * 4032 + k * 64 + b] : ((k == 0) ? 1.f : 0.f);
                    else if (k < 575)  v = ctxT[(k - 63) * 64 + b];
                    else if (k < 1087) v = h0in[(k - 575) * 64 + b];
                    else               v = 0.f;
                    xs[bcol * 66 + dk] = v;
                }
                __syncthreads();
                const float2* xr2 = (const float2*)&xs[bl * 66];
                const float4* wr4 = (const float4*)&wA[r8 * 1088 + k0];
#pragma unroll
                for (int q = 0; q < 16; ++q) {
                    float4 w4 = wr4[q];
                    float2 xa = xr2[2 * q];
                    float2 xb = xr2[2 * q + 1];
                    a4.x = fmaf(xa.x, w4.x, a4.x);
                    a4.y = fmaf(xa.y, w4.y, a4.y);
                    a4.z = fmaf(xb.x, w4.z, a4.z);
                    a4.w = fmaf(xb.y, w4.w, a4.w);
                }
            }
            float acc = a4.x + a4.y + a4.z + a4.w + cst[128 + r8];
            __syncthreads();
            ex[r8 * 32 + bl] = acc;
            __syncthreads();
            if (tid < 64) {
                int ui = tid >> 5, b32 = tid & 31;
                float gi = ex[(0 + ui) * 32 + b32];
                float gf = ex[(2 + ui) * 32 + b32];
                float gg = ex[(4 + ui) * 32 + b32];
                float go = ex[(6 + ui) * 32 + b32];
                float cv = cst[ui * 32 + b32];
                float cn = sigm(gf) * cv + sigm(gi) * tanhf(gg);
                float hn = sigm(go) * tanhf(cn);
                cst[ui * 32 + b32] = cn;
                h0out[(rg * 2 + ui) * 64 + bg * 32 + b32] = hn;
            }
        }
        gbar(bar, barTgt);

        // ---- phase B: LSTM1 ----
        {
            float* xs = ovl;
            float* ex = ovl + 2112;
            f32x4 a4 = {0.f, 0.f, 0.f, 0.f};
            for (int kc = 0; kc < 16; ++kc) {
                int k0 = kc * 64;
                __syncthreads();
#pragma unroll
                for (int i = 0; i < 8; ++i) {
                    int lidx = i * 256 + tid;
                    int dk = lidx >> 5, bcol = lidx & 31;
                    int k = k0 + dk;
                    int b = bg * 32 + bcol;
                    float v = (k < 512) ? h0out[k * 64 + b] : h1in[(k - 512) * 64 + b];
                    xs[bcol * 66 + dk] = v;
                }
                __syncthreads();
                const float2* xr2 = (const float2*)&xs[bl * 66];
                const float4* wr4 = (const float4*)&wB[r8 * 1024 + k0];
#pragma unroll
                for (int q = 0; q < 16; ++q) {
                    float4 w4 = wr4[q];
                    float2 xa = xr2[2 * q];
                    float2 xb = xr2[2 * q + 1];
                    a4.x = fmaf(xa.x, w4.x, a4.x);
                    a4.y = fmaf(xa.y, w4.y, a4.y);
                    a4.z = fmaf(xb.x, w4.z, a4.z);
                    a4.w = fmaf(xb.y, w4.w, a4.w);
                }
            }
            float acc = a4.x + a4.y + a4.z + a4.w + cst[136 + r8];
            __syncthreads();
            ex[r8 * 32 + bl] = acc;
            __syncthreads();
            if (tid < 64) {
                int ui = tid >> 5, b32 = tid & 31;
                float gi = ex[(0 + ui) * 32 + b32];
                float gf = ex[(2 + ui) * 32 + b32];
                float gg = ex[(4 + ui) * 32 + b32];
                float go = ex[(6 + ui) * 32 + b32];
                float cv = cst[64 + ui * 32 + b32];
                float cn = sigm(gf) * cv + sigm(gi) * tanhf(gg);
                float hn = sigm(go) * tanhf(cn);
                cst[64 + ui * 32 + b32] = cn;
                int u = rg * 2 + ui;
                int b = bg * 32 + b32;
                h1out[u * 64 + b] = hn;
                h1b_cur[b * 512 + u] = hn;
            }
        }
        gbar(bar, barTgt);

        // ---- phase C: char-logits(s-1) + phi comp_dec + colZero preset ----
        {
            if (s > 0) {
                int b_cp = blk >> 3;
                for (int i = tid; i < 1024; i += 256)
                    ovl[i] = (i < 512) ? h1b_prev[b_cp * 512 + i] : ctxb[b_cp * 512 + (i - 512)];
                __syncthreads();
                int c8 = tid >> 5, kl = tid & 31;
                int c = (blk & 7) * 8 + c8;
                float p = 0.f;
                if (c < 63) {
                    const float4* cw = (const float4*)&charw[(size_t)c * 1024 + kl * 32];
                    const float4* cc = (const float4*)&ovl[kl * 32];
#pragma unroll
                    for (int q = 0; q < 8; ++q) {
                        float4 w4 = cw[q], x4 = cc[q];
                        p = fmaf(x4.x, w4.x, p); p = fmaf(x4.y, w4.y, p);
                        p = fmaf(x4.z, w4.z, p); p = fmaf(x4.w, w4.w, p);
                    }
                }
                p += __shfl_xor(p, 1, 64); p += __shfl_xor(p, 2, 64);
                p += __shfl_xor(p, 4, 64); p += __shfl_xor(p, 8, 64);
                p += __shfl_xor(p, 16, 64);
                if (kl == 0 && c < 63) logit[b_cp * 64 + c] = p + charb[c];
            }
            int mg = blk >> 4, bgp = blk & 15;
            int m8 = tid >> 5, b4 = (tid >> 3) & 3, kg = tid & 7;
            int m = mg * 8 + m8, b = bgp * 4 + b4;
            float p = 0.f;
            const float4* wr = (const float4*)&phiw[(size_t)m * 512 + kg * 64];
            const float4* xr = (const float4*)&h1b_cur[b * 512 + kg * 64];
#pragma unroll
            for (int q = 0; q < 16; ++q) {
                float4 w4 = wr[q], x4 = xr[q];
                p = fmaf(x4.x, w4.x, p); p = fmaf(x4.y, w4.y, p);
                p = fmaf(x4.z, w4.z, p); p = fmaf(x4.w, w4.w, p);
            }
            p += __shfl_xor(p, 1, 64); p += __shfl_xor(p, 2, 64); p += __shfl_xor(p, 4, 64);
            if (kg == 0) cdb[b * 256 + m] = fmaxf(p + phib[m], 0.f);
            if (blk == 0)
                for (int i = tid; i < 1024; i += 256) colZero[i] = 1;
        }
        gbar(bar, barTgt);

        // ---- phase D: energy f32 (float4 x2 per lane) + preds-write(s-1) ----
        {
            int b = blk >> 3, tc = blk & 7, t0 = tc * 128;
            float* cdl = ovl;          // 256
            float* red = ovl + 256;    // 512
            cdl[tid] = cdb[b * 256 + tid];
            __syncthreads();
            int mh = tid >> 4, tg = tid & 15;
            int t8 = t0 + tg * 8;
            float acc[8] = {0.f, 0.f, 0.f, 0.f, 0.f, 0.f, 0.f, 0.f};
            const float* base = clT + ((size_t)(b * 256 + mh * 16)) * 1024 + t8;
#pragma unroll
            for (int m = 0; m < 16; ++m) {
                float4 v0 = *(const float4*)(base + (size_t)m * 1024);
                float4 v1 = *(const float4*)(base + (size_t)m * 1024 + 4);
                float c = cdl[mh * 16 + m];
                acc[0] = fmaf(c, v0.x, acc[0]);
                acc[1] = fmaf(c, v0.y, acc[1]);
                acc[2] = fmaf(c, v0.z, acc[2]);
                acc[3] = fmaf(c, v0.w, acc[3]);
                acc[4] = fmaf(c, v1.x, acc[4]);
                acc[5] = fmaf(c, v1.y, acc[5]);
                acc[6] = fmaf(c, v1.z, acc[6]);
                acc[7] = fmaf(c, v1.w, acc[7]);
            }
#pragma unroll
            for (int j = 0; j < 8; ++j) {
                acc[j] += __shfl_xor(acc[j], 16, 64);
                acc[j] += __shfl_xor(acc[j], 32, 64);
            }
            int w = tid >> 6;
            if (((tid >> 4) & 3) == 0) {
#pragma unroll
                for (int j = 0; j < 8; ++j) red[w * 128 + tg * 8 + j] = acc[j];
            }
            __syncthreads();
            if (tid < 128) {
                float sum = red[tid] + red[128 + tid] + red[256 + tid] + red[384 + tid];
                int t = t0 + tid;
                energyT[t * 64 + b] = sum;
                if (sum != 0.f) colZero[t] = 0;
            }
            if (tc == 0 && s > 0 && tid < 64) {
                int c = tid;
                float lg = (c < 63) ? logit[b * 64 + c] : -1e30f;
                float mx = lg;
                for (int o = 32; o > 0; o >>= 1) mx = fmaxf(mx, __shfl_xor(mx, o, 64));
                float ex2 = (c < 63) ? __expf(lg - mx) : 0.f;
                float sume = wsum64(ex2);
                if (c < 63)
                    preds[((size_t)(s - 1) * B_ + b) * CC + c] = lg - mx - __logf(sume);
            }
        }
        gbar(bar, barTgt);

        // ---- phase E: copula stats + vals (blocks 0..255, 4 t per block) ----
        {
            int* zred = (int*)ovl;
            if (blk < 256) {
                int zacc = colZero[tid] | colZero[256 + tid] | colZero[512 + tid] | colZero[768 + tid];
                zred[tid] = zacc;
                __syncthreads();
                for (int o = 128; o > 0; o >>= 1) {
                    if (tid < o) zred[tid] |= zred[tid + o];
                    __syncthreads();
                }
                int zf = zred[0];
                int wv = tid >> 6, b = tid & 63;
                int t = blk * 4 + wv;
                float e = energyT[t * 64 + b];
                float a = (t > 0) ? energyT[(t - 1) * 64 + b] : 0.f;
                float val;
                if (zf) {
                    val = e;
                } else {
                    float cp;
                    if (t >= 1 && t < 1023) {
                        float ma = wsum64(a) * (1.f / 64.f);
                        float mb = wsum64(e) * (1.f / 64.f);
                        float am = a - ma, bm = e - mb;
                        float sab = wsum64(am * bm);
                        float saa = wsum64(am * am);
                        float sbb = wsum64(bm * bm);
                        int aeq = __all(a == e);
                        float r = sab / sqrtf(saa * sbb + 1e-12f);
                        float det = 1.f - r * r;
                        if (det < 0.01f || aeq) cp = 10.f;
                        else {
                            float ds = fmaxf(det, 1e-6f);
                            float quad = r * r * (a * a + e * e) - 2.f * r * a * e;
                            cp = __expf(-0.5f * quad / ds) / sqrtf(ds);
                        }
                    } else {
                        cp = 1.f;
                    }
                    float pdf = __expf(-0.5f * e * e) * INV_SQRT_2PI;
                    val = pdf * cp;
                }
                vbuf[b * 1024 + t] = val;
            }
        }
        gbar(bar, barTgt);

        // ---- phase F: softmax + atts + context (16B/lane loads) ----
        {
            int b = blk >> 3, dq = blk & 7, d0 = dq * 64;
            float* att = ovl;            // padded: att[t + (t>>5)], 1056
            float* red = ovl + 1056;     // 256
            float* red2 = ovl + 1312;    // 256
            float4 v4 = *(const float4*)&vbuf[b * 1024 + tid * 4];
            float lm = fmaxf(fmaxf(v4.x, v4.y), fmaxf(v4.z, v4.w));
            red[tid] = lm;
            __syncthreads();
            for (int o = 128; o > 0; o >>= 1) {
                if (tid < o) red[tid] = fmaxf(red[tid], red[tid + o]);
                __syncthreads();
            }
            float M = red[0];
            __syncthreads();
            float e0 = __expf(v4.x - M), e1 = __expf(v4.y - M);
            float e2 = __expf(v4.z - M), e3 = __expf(v4.w - M);
            red[tid] = e0 + e1 + e2 + e3;
            __syncthreads();
            for (int o = 128; o > 0; o >>= 1) {
                if (tid < o) red[tid] += red[tid + o];
                __syncthreads();
            }
            float inv = 1.f / red[0];
            int pb = tid * 4 + (tid >> 3);
            att[pb] = e0 * inv; att[pb + 1] = e1 * inv;
            att[pb + 2] = e2 * inv; att[pb + 3] = e3 * inv;
            if (dq == 0)
                *(float4*)&atts[((size_t)s * B_ + b) * 1024 + tid * 4] =
                    make_float4(e0 * inv, e1 * inv, e2 * inv, e3 * inv);
            __syncthreads();
            int tc = tid >> 3, dg = tid & 7;
            int d8 = d0 + dg * 8;
            float acc[8] = {0.f, 0.f, 0.f, 0.f, 0.f, 0.f, 0.f, 0.f};
            if (useBf) {
                const unsigned short* Lb = Lbf + (size_t)b * 524288 + (size_t)(tc * 32) * 512 + d8;
#pragma unroll
                for (int i = 0; i < 32; ++i) {
                    float wv2 = att[tc * 33 + i];
                    short8v v = *(const short8v*)(Lb + (size_t)i * 512);
                    acc[0] = fmaf(wv2, bf2f((unsigned short)v[0]), acc[0]);
                    acc[1] = fmaf(wv2, bf2f((unsigned short)v[1]), acc[1]);
                    acc[2] = fmaf(wv2, bf2f((unsigned short)v[2]), acc[2]);
                    acc[3] = fmaf(wv2, bf2f((unsigned short)v[3]), acc[3]);
                    acc[4] = fmaf(wv2, bf2f((unsigned short)v[4]), acc[4]);
                    acc[5] = fmaf(wv2, bf2f((unsigned short)v[5]), acc[5]);
                    acc[6] = fmaf(wv2, bf2f((unsigned short)v[6]), acc[6]);
                    acc[7] = fmaf(wv2, bf2f((unsigned short)v[7]), acc[7]);
                }
            } else {
                const float* Lp = Lf + (size_t)b * 524288 + (size_t)(tc * 32) * 512 + d8;
#pragma unroll
                for (int i = 0; i < 32; ++i) {
                    float wv2 = att[tc * 33 + i];
                    float4 u0 = *(const float4*)(Lp + (size_t)i * 512);
                    float4 u1 = *(const float4*)(Lp + (size_t)i * 512 + 4);
                    acc[0] = fmaf(wv2, u0.x, acc[0]); acc[1] = fmaf(wv2, u0.y, acc[1]);
                    acc[2] = fmaf(wv2, u0.z, acc[2]); acc[3] = fmaf(wv2, u0.w, acc[3]);
                    acc[4] = fmaf(wv2, u1.x, acc[4]); acc[5] = fmaf(wv2, u1.y, acc[5]);
                    acc[6] = fmaf(wv2, u1.z, acc[6]); acc[7] = fmaf(wv2, u1.w, acc[7]);
                }
            }
#pragma unroll
            for (int j = 0; j < 8; ++j) {
                acc[j] += __shfl_xor(acc[j], 8, 64);
                acc[j] += __shfl_xor(acc[j], 16, 64);
                acc[j] += __shfl_xor(acc[j], 32, 64);
            }
            int w = tid >> 6;
            if ((tid & 56) == 0) {
#pragma unroll
                for (int j = 0; j < 8; ++j) red2[w * 64 + dg * 8 + j] = acc[j];
            }
            __syncthreads();
            if (tid < 64) {
                float cv = red2[tid] + red2[64 + tid] + red2[128 + tid] + red2[192 + tid];
                ctxT[(d0 + tid) * 64 + b] = cv;
                ctxb[b * 512 + d0 + tid] = cv;
            }
        }
        gbar(bar, barTgt);
    }

    // ---- tail: char-logits + preds for s=63 (h1b of step 63 = buffer 0) ----
    {
        int b_cp = blk >> 3;
        for (int i = tid; i < 1024; i += 256)
            ovl[i] = (i < 512) ? h1bb[b_cp * 512 + i] : ctxb[b_cp * 512 + (i - 512)];
        __syncthreads();
        int c8 = tid >> 5, kl = tid & 31;
        int c = (blk & 7) * 8 + c8;
        float p = 0.f;
        if (c < 63) {
            const float4* cw = (const float4*)&charw[(size_t)c * 1024 + kl * 32];
            const float4* cc = (const float4*)&ovl[kl * 32];
#pragma unroll
            for (int q = 0; q < 8; ++q) {
                float4 w4 = cw[q], x4 = cc[q];
                p = fmaf(x4.x, w4.x, p); p = fmaf(x4.y, w4.y, p);
                p = fmaf(x4.z, w4.z, p); p = fmaf(x4.w, w4.w, p);
            }
        }
        p += __shfl_xor(p, 1, 64); p += __shfl_xor(p, 2, 64);
        p += __shfl_xor(p, 4, 64); p += __shfl_xor(p, 8, 64);
        p += __shfl_xor(p, 16, 64);
        if (kl == 0 && c < 63) logit[b_cp * 64 + c] = p + charb[c];
    }
    gbar(bar, barTgt);
    if (blk < 64 && tid < 64) {
        int b = blk, c = tid;
        float lg = (c < 63) ? logit[b * 64 + c] : -1e30f;
        float mx = lg;
        for (int o = 32; o > 0; o >>= 1) mx = fmaxf(mx, __shfl_xor(mx, o, 64));
        float ex2 = (c < 63) ? __expf(lg - mx) : 0.f;
        float sume = wsum64(ex2);
        if (c < 63)
            preds[((size_t)(SS - 1) * B_ + b) * CC + c] = lg - mx - __logf(sume);
    }
}

extern "C" void kernel_launch(void* const* d_in, const int* in_sizes, int n_in,
                              void* d_out, int out_size, void* d_ws, size_t ws_size,
                              hipStream_t stream) {
    const float* Lf   = (const float*)d_in[0];
    const float* gt   = (const float*)d_in[1];
    const float* phiw = (const float*)d_in[2];
    const float* phib = (const float*)d_in[3];
    const float* psiw = (const float*)d_in[4];
    const float* psib = (const float*)d_in[5];
    const float* wih0 = (const float*)d_in[6];
    const float* whh0 = (const float*)d_in[7];
    const float* bih0 = (const float*)d_in[8];
    const float* bhh0 = (const float*)d_in[9];
    const float* wih1 = (const float*)d_in[10];
    const float* whh1 = (const float*)d_in[11];
    const float* bih1 = (const float*)d_in[12];
    const float* bhh1 = (const float*)d_in[13];
    const float* charw = (const float*)d_in[14];
    const float* charb = (const float*)d_in[15];

    float* preds = (float*)d_out;
    float* atts  = (float*)d_out + (size_t)SS * B_ * CC;

    char* ws = (char*)d_ws;
    size_t off = 0;
    auto alloc = [&](size_t bytes) { size_t o = off; off = (off + bytes + 255) & ~(size_t)255; return o; };
    float* clT     = (float*)(ws + alloc((size_t)B_ * M_ * T_ * 4));   // f32 now
    float* gtT     = (float*)(ws + alloc((size_t)SS * CC * 64 * 4));
    float* h0buf   = (float*)(ws + alloc(2 * H_ * B_ * 4));
    float* h1buf   = (float*)(ws + alloc(2 * H_ * B_ * 4));
    float* h1bb    = (float*)(ws + alloc(2 * H_ * B_ * 4));
    float* ctxT    = (float*)(ws + alloc(H_ * B_ * 4));
    float* ctxb    = (float*)(ws + alloc(H_ * B_ * 4));
    float* energyT = (float*)(ws + alloc(B_ * T_ * 4));
    float* vbuf    = (float*)(ws + alloc(B_ * T_ * 4));
    float* cdb     = (float*)(ws + alloc(B_ * M_ * 4));
    float* logit   = (float*)(ws + alloc(B_ * 64 * 4));
    int* colZero   = (int*)(ws + alloc(1024 * 4));
    int* bar       = (int*)(ws + alloc(256));
    size_t baseNeed = off;
    size_t lbfBytes = (size_t)B_ * T_ * D_ * 2;
    int useBf = (baseNeed + lbfBytes + 256 <= ws_size) ? 1 : 0;
    unsigned short* Lbf = (unsigned short*)(ws + (useBf ? alloc(lbfBytes) : 0));

    hipMemsetAsync(bar, 0, 256, stream);
    k_gemm<<<4096, 256, 0, stream>>>(Lf, psiw, psib, clT);
    if (useBf) k_conv<<<2048, 256, 0, stream>>>(Lf, Lbf, (B_ * T_ * D_) / 4);
    k_mega<<<NBLK, 256, 0, stream>>>(Lf, Lbf, useBf, gt,
                                     phiw, phib, wih0, whh0, bih0, bhh0,
                                     wih1, whh1, bih1, bhh1, charw, charb,
                                     clT, gtT, h0buf, h1buf, h1bb,
                                     ctxT, ctxb, energyT, vbuf,
                                     cdb, logit, colZero, bar, preds, atts);
}

// Round 6
// 18102.861 us; speedup vs baseline: 1.2388x; 1.2388x over previous
//
#include <hip/hip_runtime.h>
#include <hip/hip_bf16.h>
#include <math.h>

#define B_ 64
#define T_ 1024
#define D_ 512
#define H_ 512
#define M_ 256
#define CC 63
#define SS 64
#define NBLK 1024
#define INV_SQRT_2PI 0.3989422804014327f

typedef __attribute__((ext_vector_type(8))) short short8v;

static __device__ __forceinline__ float bf2f(unsigned short u) {
    unsigned int x = ((unsigned int)u) << 16;
    return __uint_as_float(x);
}
static __device__ __forceinline__ unsigned short f2bf(float f) {
    unsigned int x = __float_as_uint(f);
    unsigned int r = (x + 0x7fff + ((x >> 16) & 1)) >> 16;
    return (unsigned short)r;
}
static __device__ __forceinline__ float sigm(float x) {
    return 1.f / (1.f + __expf(-x));
}
static __device__ __forceinline__ float wsum64(float v) {
    for (int o = 32; o > 0; o >>= 1) v += __shfl_xor(v, o, 64);
    return v;
}

// two-level tree barrier: 16 groups x 64 blocks, counters on separate cachelines.
// bar ints: arrive[gid] @ gid*32; release flag[gid] @ 512+gid*32; global @ 1024.
static __device__ __forceinline__ void gbar(int* bar, int& epoch) {
    epoch += 1;
    __syncthreads();
    if (threadIdx.x == 0) {
        __builtin_amdgcn_fence(__ATOMIC_RELEASE, "agent");
        int gid = blockIdx.x >> 6;
        int v = __hip_atomic_fetch_add(bar + gid * 32, 1, __ATOMIC_RELAXED, __HIP_MEMORY_SCOPE_AGENT);
        if (v == epoch * 64 - 1) {
            int g = __hip_atomic_fetch_add(bar + 1024, 1, __ATOMIC_RELAXED, __HIP_MEMORY_SCOPE_AGENT);
            if (g == epoch * 16 - 1) {
#pragma unroll
                for (int i = 0; i < 16; ++i)
                    __hip_atomic_store(bar + 512 + i * 32, epoch, __ATOMIC_RELAXED, __HIP_MEMORY_SCOPE_AGENT);
            }
        }
        while (__hip_atomic_load(bar + 512 + gid * 32, __ATOMIC_RELAXED, __HIP_MEMORY_SCOPE_AGENT) < epoch) {
            __builtin_amdgcn_s_sleep(2);
        }
        __builtin_amdgcn_fence(__ATOMIC_ACQUIRE, "agent");
    }
    __syncthreads();
}

// ---------------- prologue kernels (proven round-5) ----------------

__global__ __launch_bounds__(256) void k_conv(const float* __restrict__ src,
        unsigned short* __restrict__ dst, int n4) {
    int stride = gridDim.x * 256;
    for (int i = blockIdx.x * 256 + threadIdx.x; i < n4; i += stride) {
        float4 v = ((const float4*)src)[i];
        ushort4 o;
        o.x = f2bf(v.x); o.y = f2bf(v.y); o.z = f2bf(v.z); o.w = f2bf(v.w);
        ((ushort4*)dst)[i] = o;
    }
}

// f32 GEMM: clT[b*256+m][t] = relu(sum_d L[b*1024+t][d]*psi[m][d] + psib[m])
__global__ __launch_bounds__(256) void k_gemm(const float* __restrict__ Lf,
        const float* __restrict__ psiw, const float* __restrict__ psib,
        float* __restrict__ clT) {
    __shared__ float At[64 * 65];
    __shared__ float Bt[64 * 65];
    int tid = threadIdx.x;
    int pt = blockIdx.x >> 2;
    int mt = blockIdx.x & 3;
    int p0 = pt * 64, m0 = mt * 64;
    int tp = tid >> 4, tm = tid & 15;
    float acc[4][4] = {{0.f}};
    for (int k0 = 0; k0 < 512; k0 += 64) {
        __syncthreads();
        for (int i = 0; i < 16; ++i) {
            int lidx = i * 256 + tid;
            int r = lidx >> 6, c = lidx & 63;
            At[r * 65 + c] = Lf[(size_t)(p0 + r) * 512 + k0 + c];
            Bt[r * 65 + c] = psiw[(size_t)(m0 + r) * 512 + k0 + c];
        }
        __syncthreads();
        for (int dk = 0; dk < 64; ++dk) {
            float av[4], bv[4];
#pragma unroll
            for (int i = 0; i < 4; ++i) av[i] = At[(4 * tp + i) * 65 + dk];
#pragma unroll
            for (int j = 0; j < 4; ++j) bv[j] = Bt[(4 * tm + j) * 65 + dk];
#pragma unroll
            for (int i = 0; i < 4; ++i)
#pragma unroll
                for (int j = 0; j < 4; ++j)
                    acc[i][j] = fmaf(av[i], bv[j], acc[i][j]);
        }
    }
#pragma unroll
    for (int i = 0; i < 4; ++i) {
        int p = p0 + 4 * tp + i;
        int b = p >> 10, t = p & 1023;
#pragma unroll
        for (int j = 0; j < 4; ++j) {
            int m = m0 + 4 * tm + j;
            clT[((size_t)(b * 256 + m)) * 1024 + t] = fmaxf(acc[i][j] + psib[m], 0.f);
        }
    }
}

// ---------------- persistent mega kernel, 1024 blocks ----------------

static __device__ __forceinline__ void charpred_logits(int bcp, int cc, int tid,
        const float* __restrict__ h1bvec, const float* __restrict__ ctxb,
        const float* __restrict__ charw, const float* __restrict__ charb,
        float* __restrict__ logit, float* ovl) {
    for (int i = tid; i < 1024; i += 256)
        ovl[i] = (i < 512) ? h1bvec[bcp * 512 + i] : ctxb[bcp * 512 + (i - 512)];
    __syncthreads();
    int c8 = tid >> 5, kl = tid & 31;
    int c = cc * 8 + c8;
    float p = 0.f;
    if (c < 63) {
        const float4* cw = (const float4*)&charw[(size_t)c * 1024 + kl * 32];
        const float4* cx = (const float4*)&ovl[kl * 32];
#pragma unroll
        for (int q = 0; q < 8; ++q) {
            float4 w4 = cw[q], x4 = cx[q];
            p = fmaf(x4.x, w4.x, p); p = fmaf(x4.y, w4.y, p);
            p = fmaf(x4.z, w4.z, p); p = fmaf(x4.w, w4.w, p);
        }
    }
    p += __shfl_xor(p, 1, 64); p += __shfl_xor(p, 2, 64);
    p += __shfl_xor(p, 4, 64); p += __shfl_xor(p, 8, 64);
    p += __shfl_xor(p, 16, 64);
    if (kl == 0 && c < 63) logit[bcp * 64 + c] = p + charb[c];
}

__global__ __launch_bounds__(256, 4) void k_mega(
        const unsigned short* __restrict__ Lbf, const float* __restrict__ Lf,
        const float* __restrict__ gt,
        const float* __restrict__ phiw, const float* __restrict__ phib,
        const float* __restrict__ wih0, const float* __restrict__ whh0,
        const float* __restrict__ bih0, const float* __restrict__ bhh0,
        const float* __restrict__ wih1, const float* __restrict__ whh1,
        const float* __restrict__ bih1, const float* __restrict__ bhh1,
        const float* __restrict__ charw, const float* __restrict__ charb,
        const float* __restrict__ clT,
        float* gtT, float* h0buf, float* h1buf, float* h1bb,
        float* ctxT, float* ctxb, float* energyT, float* vbuf,
        float* cdb, float* logit, int* colZero, int* bar,
        float* preds, float* atts) {
    __shared__ float wgt[4352];                // 4 rows x 1088 (L0) or 4 x 1024 (L1)
    __shared__ __align__(16) float ovl[2048];  // 8KB per-phase overlay
    __shared__ float cst[68];                  // c[64] + bias[4]

    int tid = threadIdx.x, blk = blockIdx.x;
    int epoch = 0;
    bool isL0 = blk < 512;
    int u = isL0 ? blk : blk - 512;            // owned LSTM unit

    // ---- INIT ----
    if (isL0) {
        for (int g = 0; g < 4; ++g) {
            int j = g * 512 + u;
            for (int k = tid; k < 1088; k += 256)
                wgt[g * 1088 + k] = (k < 575) ? wih0[(size_t)j * 575 + k]
                                  : (k < 1087) ? whh0[(size_t)j * 512 + (k - 575)] : 0.f;
        }
        if (tid < 4) cst[64 + tid] = bih0[tid * 512 + u] + bhh0[tid * 512 + u];
    } else {
        for (int g = 0; g < 4; ++g) {
            int j = g * 512 + u;
            for (int k = tid; k < 1024; k += 256)
                wgt[g * 1024 + k] = (k < 512) ? wih1[(size_t)j * 512 + k]
                                              : whh1[(size_t)j * 512 + (k - 512)];
        }
        if (tid < 4) cst[64 + tid] = bih1[tid * 512 + u] + bhh1[tid * 512 + u];
    }
    if (tid < 64) cst[tid] = 0.f;
    if (blk < 64) {
        int s0 = blk;
        for (int r = tid; r < CC * 64; r += 256) {
            int k = r >> 6, b = r & 63;
            gtT[s0 * (CC * 64) + r] = gt[(b * SS + s0) * CC + k];
        }
    } else if (blk < 192) {
        int idx = (blk - 64) * 256 + tid;
        h0buf[idx] = 0.f;
        h1buf[idx] = 0.f;
        int d = idx >> 6, b = idx & 63;
        float v = Lf[(size_t)b * (T_ * D_) + d];
        ctxT[idx] = v;
        ctxb[b * 512 + d] = v;
    }
    gbar(bar, epoch);

    for (int s = 0; s < SS; ++s) {
        int pin = s & 1;
        const float* h0in = h0buf + pin * 32768;
        float* h0out = h0buf + (1 - pin) * 32768;
        const float* h1in = h1buf + pin * 32768;
        float* h1out = h1buf + (1 - pin) * 32768;
        const float* h1b_prev = h1bb + pin * 32768;
        float* h1b_cur = h1bb + (1 - pin) * 32768;

        // ---- phase A: LSTM0 (blocks 0-511) || char-logits(s-1) (blocks 512-1023) ----
        if (isL0) {
            int g = tid >> 6, b = tid & 63;
            const float* wr = wgt + g * 1088;
            float acc = 0.f;
            for (int kc = 0; kc < 34; ++kc) {
                int k0 = kc * 32;
                __syncthreads();
#pragma unroll
                for (int i = 0; i < 2; ++i) {
                    int e = i * 1024 + tid * 4;
                    int k = k0 + (e >> 6), b4 = e & 63;
                    float4 v;
                    if (k < 63) {
                        if (s > 0) v = *(const float4*)&gtT[(s - 1) * 4032 + k * 64 + b4];
                        else { float o1 = (k == 0) ? 1.f : 0.f; v = make_float4(o1, o1, o1, o1); }
                    } else if (k < 575)  v = *(const float4*)&ctxT[(k - 63) * 64 + b4];
                    else if (k < 1087)   v = *(const float4*)&h0in[(k - 575) * 64 + b4];
                    else                 v = make_float4(0.f, 0.f, 0.f, 0.f);
                    *(float4*)&ovl[e] = v;
                }
                __syncthreads();
#pragma unroll
                for (int kk = 0; kk < 32; ++kk)
                    acc = fmaf(ovl[kk * 64 + b], wr[k0 + kk], acc);
            }
            acc += cst[64 + g];
            __syncthreads();
            ovl[g * 64 + b] = acc;
            __syncthreads();
            if (tid < 64) {
                float gi = ovl[tid], gf = ovl[64 + tid], gg = ovl[128 + tid], go = ovl[192 + tid];
                float cv = cst[tid];
                float cn = sigm(gf) * cv + sigm(gi) * tanhf(gg);
                float hn = sigm(go) * tanhf(cn);
                cst[tid] = cn;
                h0out[u * 64 + tid] = hn;
            }
        } else if (s > 0) {
            charpred_logits((blk - 512) >> 3, (blk - 512) & 7, tid,
                            h1b_prev, ctxb, charw, charb, logit, ovl);
        }
        gbar(bar, epoch);

        // ---- phase B: LSTM1 (512-1023) || preds-write(s-1) (0-63) || colZero (64) ----
        if (!isL0) {
            int g = tid >> 6, b = tid & 63;
            const float* wr = wgt + g * 1024;
            float acc = 0.f;
            for (int kc = 0; kc < 32; ++kc) {
                int k0 = kc * 32;
                __syncthreads();
#pragma unroll
                for (int i = 0; i < 2; ++i) {
                    int e = i * 1024 + tid * 4;
                    int k = k0 + (e >> 6), b4 = e & 63;
                    float4 v = (k < 512) ? *(const float4*)&h0out[k * 64 + b4]
                                         : *(const float4*)&h1in[(k - 512) * 64 + b4];
                    *(float4*)&ovl[e] = v;
                }
                __syncthreads();
#pragma unroll
                for (int kk = 0; kk < 32; ++kk)
                    acc = fmaf(ovl[kk * 64 + b], wr[k0 + kk], acc);
            }
            acc += cst[64 + g];
            __syncthreads();
            ovl[g * 64 + b] = acc;
            __syncthreads();
            if (tid < 64) {
                float gi = ovl[tid], gf = ovl[64 + tid], gg = ovl[128 + tid], go = ovl[192 + tid];
                float cv = cst[tid];
                float cn = sigm(gf) * cv + sigm(gi) * tanhf(gg);
                float hn = sigm(go) * tanhf(cn);
                cst[tid] = cn;
                h1out[u * 64 + tid] = hn;
                h1b_cur[tid * 512 + u] = hn;
            }
        } else if (blk < 64) {
            if (s > 0 && tid < 64) {
                int b = blk, c = tid;
                float lg = (c < 63) ? logit[b * 64 + c] : -1e30f;
                float mx = lg;
                for (int o = 32; o > 0; o >>= 1) mx = fmaxf(mx, __shfl_xor(mx, o, 64));
                float ex2 = (c < 63) ? __expf(lg - mx) : 0.f;
                float sume = wsum64(ex2);
                if (c < 63)
                    preds[((size_t)(s - 1) * B_ + b) * CC + c] = lg - mx - __logf(sume);
            }
        } else if (blk == 64) {
            for (int i = tid; i < 1024; i += 256) colZero[i] = 1;
        }
        gbar(bar, epoch);

        // ---- phase C: phi comp_dec (blocks 0-511, r5-verbatim) ----
        if (isL0) {
            int mg = blk >> 4, bgp = blk & 15;
            int m8 = tid >> 5, b4 = (tid >> 3) & 3, kg = tid & 7;
            int m = mg * 8 + m8, b = bgp * 4 + b4;
            float p = 0.f;
            const float4* wr = (const float4*)&phiw[(size_t)m * 512 + kg * 64];
            const float4* xr = (const float4*)&h1b_cur[b * 512 + kg * 64];
#pragma unroll
            for (int q = 0; q < 16; ++q) {
                float4 w4 = wr[q], x4 = xr[q];
                p = fmaf(x4.x, w4.x, p); p = fmaf(x4.y, w4.y, p);
                p = fmaf(x4.z, w4.z, p); p = fmaf(x4.w, w4.w, p);
            }
            p += __shfl_xor(p, 1, 64); p += __shfl_xor(p, 2, 64); p += __shfl_xor(p, 4, 64);
            if (kg == 0) cdb[b * 256 + m] = fmaxf(p + phib[m], 0.f);
        }
        gbar(bar, epoch);

        // ---- phase D: energy f32 (1024 blocks: b x 16 t-chunks of 64; r5 sum order) ----
        {
            int b = blk >> 4, tc = blk & 15, t0 = tc * 64;
            float* cdl = ovl;          // 256
            float* red = ovl + 256;    // 256
            cdl[tid] = cdb[b * 256 + tid];
            __syncthreads();
            int mh = tid >> 4, tg = tid & 15;
            int t4 = t0 + tg * 4;
            float acc[4] = {0.f, 0.f, 0.f, 0.f};
            const float* base = clT + ((size_t)(b * 256 + mh * 16)) * 1024 + t4;
#pragma unroll
            for (int m = 0; m < 16; ++m) {
                float4 v0 = *(const float4*)(base + (size_t)m * 1024);
                float c = cdl[mh * 16 + m];
                acc[0] = fmaf(c, v0.x, acc[0]);
                acc[1] = fmaf(c, v0.y, acc[1]);
                acc[2] = fmaf(c, v0.z, acc[2]);
                acc[3] = fmaf(c, v0.w, acc[3]);
            }
#pragma unroll
            for (int j = 0; j < 4; ++j) {
                acc[j] += __shfl_xor(acc[j], 16, 64);
                acc[j] += __shfl_xor(acc[j], 32, 64);
            }
            int w = tid >> 6;
            if (((tid >> 4) & 3) == 0) {
#pragma unroll
                for (int j = 0; j < 4; ++j) red[w * 64 + tg * 4 + j] = acc[j];
            }
            __syncthreads();
            if (tid < 64) {
                float sum = red[tid] + red[64 + tid] + red[128 + tid] + red[192 + tid];
                int t = t0 + tid;
                energyT[t * 64 + b] = sum;
                if (sum != 0.f) colZero[t] = 0;
            }
        }
        gbar(bar, epoch);

        // ---- phase E: copula stats + vals (blocks 0-255, r5-verbatim) ----
        {
            int* zred = (int*)ovl;
            if (blk < 256) {
                int zacc = colZero[tid] | colZero[256 + tid] | colZero[512 + tid] | colZero[768 + tid];
                zred[tid] = zacc;
                __syncthreads();
                for (int o = 128; o > 0; o >>= 1) {
                    if (tid < o) zred[tid] |= zred[tid + o];
                    __syncthreads();
                }
                int zf = zred[0];
                int wv = tid >> 6, b = tid & 63;
                int t = blk * 4 + wv;
                float e = energyT[t * 64 + b];
                float a = (t > 0) ? energyT[(t - 1) * 64 + b] : 0.f;
                float val;
                if (zf) {
                    val = e;
                } else {
                    float cp;
                    if (t >= 1 && t < 1023) {
                        float ma = wsum64(a) * (1.f / 64.f);
                        float mb = wsum64(e) * (1.f / 64.f);
                        float am = a - ma, bm = e - mb;
                        float sab = wsum64(am * bm);
                        float saa = wsum64(am * am);
                        float sbb = wsum64(bm * bm);
                        int aeq = __all(a == e);
                        float r = sab / sqrtf(saa * sbb + 1e-12f);
                        float det = 1.f - r * r;
                        if (det < 0.01f || aeq) cp = 10.f;
                        else {
                            float ds = fmaxf(det, 1e-6f);
                            float quad = r * r * (a * a + e * e) - 2.f * r * a * e;
                            cp = __expf(-0.5f * quad / ds) / sqrtf(ds);
                        }
                    } else {
                        cp = 1.f;
                    }
                    float pdf = __expf(-0.5f * e * e) * INV_SQRT_2PI;
                    val = pdf * cp;
                }
                vbuf[b * 1024 + t] = val;
            }
        }
        gbar(bar, epoch);

        // ---- phase F: softmax + atts + context (1024 blocks: b x 16 d-chunks of 32) ----
        {
            int b = blk >> 4, dq = blk & 15, d0 = dq * 32;
            float* red = ovl;           // 256
            float* red2 = ovl + 256;    // 128
            float4 v4 = *(const float4*)&vbuf[b * 1024 + tid * 4];
            float lm = fmaxf(fmaxf(v4.x, v4.y), fmaxf(v4.z, v4.w));
            red[tid] = lm;
            __syncthreads();
            for (int o = 128; o > 0; o >>= 1) {
                if (tid < o) red[tid] = fmaxf(red[tid], red[tid + o]);
                __syncthreads();
            }
            float M = red[0];
            __syncthreads();
            float e0 = __expf(v4.x - M), e1 = __expf(v4.y - M);
            float e2 = __expf(v4.z - M), e3 = __expf(v4.w - M);
            red[tid] = e0 + e1 + e2 + e3;
            __syncthreads();
            for (int o = 128; o > 0; o >>= 1) {
                if (tid < o) red[tid] += red[tid + o];
                __syncthreads();
            }
            float inv = 1.f / red[0];
            float4 a4 = make_float4(e0 * inv, e1 * inv, e2 * inv, e3 * inv);
            if (dq == 0)
                *(float4*)&atts[((size_t)s * B_ + b) * 1024 + tid * 4] = a4;
            __syncthreads();
            // context: thread owns 8 d, 64 t-groups of 16 t; att fetched via in-wave shfl
            int tc = tid >> 2, dg = tid & 3;
            int d8 = d0 + dg * 8;
            float acc[8] = {0.f, 0.f, 0.f, 0.f, 0.f, 0.f, 0.f, 0.f};
            const unsigned short* Lb = Lbf + (size_t)b * 524288 + (size_t)(tc * 16) * 512 + d8;
#pragma unroll
            for (int q = 0; q < 4; ++q) {
                int src = (tc * 4 + q) & 63;
                float av0 = __shfl(a4.x, src, 64);
                float av1 = __shfl(a4.y, src, 64);
                float av2 = __shfl(a4.z, src, 64);
                float av3 = __shfl(a4.w, src, 64);
                float avs[4] = {av0, av1, av2, av3};
#pragma unroll
                for (int e = 0; e < 4; ++e) {
                    float wv2 = avs[e];
                    short8v v = *(const short8v*)(Lb + (size_t)(q * 4 + e) * 512);
                    acc[0] = fmaf(wv2, bf2f((unsigned short)v[0]), acc[0]);
                    acc[1] = fmaf(wv2, bf2f((unsigned short)v[1]), acc[1]);
                    acc[2] = fmaf(wv2, bf2f((unsigned short)v[2]), acc[2]);
                    acc[3] = fmaf(wv2, bf2f((unsigned short)v[3]), acc[3]);
                    acc[4] = fmaf(wv2, bf2f((unsigned short)v[4]), acc[4]);
                    acc[5] = fmaf(wv2, bf2f((unsigned short)v[5]), acc[5]);
                    acc[6] = fmaf(wv2, bf2f((unsigned short)v[6]), acc[6]);
                    acc[7] = fmaf(wv2, bf2f((unsigned short)v[7]), acc[7]);
                }
            }
#pragma unroll
            for (int j = 0; j < 8; ++j) {
                acc[j] += __shfl_xor(acc[j], 4, 64);
                acc[j] += __shfl_xor(acc[j], 8, 64);
                acc[j] += __shfl_xor(acc[j], 16, 64);
                acc[j] += __shfl_xor(acc[j], 32, 64);
            }
            int w = tid >> 6;
            if ((tid & 60) == 0) {
#pragma unroll
                for (int j = 0; j < 8; ++j) red2[w * 32 + dg * 8 + j] = acc[j];
            }
            __syncthreads();
            if (tid < 32) {
                float cv = red2[tid] + red2[32 + tid] + red2[64 + tid] + red2[96 + tid];
                ctxT[(d0 + tid) * 64 + b] = cv;
                ctxb[b * 512 + d0 + tid] = cv;
            }
        }
        gbar(bar, epoch);
    }

    // ---- tail: char-logits(s=63) on blocks 512-1023, then preds-write ----
    if (!isL0) {
        charpred_logits((blk - 512) >> 3, (blk - 512) & 7, tid,
                        h1bb, ctxb, charw, charb, logit, ovl);
    }
    gbar(bar, epoch);
    if (blk < 64 && tid < 64) {
        int b = blk, c = tid;
        float lg = (c < 63) ? logit[b * 64 + c] : -1e30f;
        float mx = lg;
        for (int o = 32; o > 0; o >>= 1) mx = fmaxf(mx, __shfl_xor(mx, o, 64));
        float ex2 = (c < 63) ? __expf(lg - mx) : 0.f;
        float sume = wsum64(ex2);
        if (c < 63)
            preds[((size_t)(SS - 1) * B_ + b) * CC + c] = lg - mx - __logf(sume);
    }
}

extern "C" void kernel_launch(void* const* d_in, const int* in_sizes, int n_in,
                              void* d_out, int out_size, void* d_ws, size_t ws_size,
                              hipStream_t stream) {
    const float* Lf   = (const float*)d_in[0];
    const float* gt   = (const float*)d_in[1];
    const float* phiw = (const float*)d_in[2];
    const float* phib = (const float*)d_in[3];
    const float* psiw = (const float*)d_in[4];
    const float* psib = (const float*)d_in[5];
    const float* wih0 = (const float*)d_in[6];
    const float* whh0 = (const float*)d_in[7];
    const float* bih0 = (const float*)d_in[8];
    const float* bhh0 = (const float*)d_in[9];
    const float* wih1 = (const float*)d_in[10];
    const float* whh1 = (const float*)d_in[11];
    const float* bih1 = (const float*)d_in[12];
    const float* bhh1 = (const float*)d_in[13];
    const float* charw = (const float*)d_in[14];
    const float* charb = (const float*)d_in[15];

    float* preds = (float*)d_out;
    float* atts  = (float*)d_out + (size_t)SS * B_ * CC;

    char* ws = (char*)d_ws;
    size_t off = 0;
    auto alloc = [&](size_t bytes) { size_t o = off; off = (off + bytes + 255) & ~(size_t)255; return o; };
    float* clT     = (float*)(ws + alloc((size_t)B_ * M_ * T_ * 4));
    float* gtT     = (float*)(ws + alloc((size_t)SS * CC * 64 * 4));
    float* h0buf   = (float*)(ws + alloc(2 * H_ * B_ * 4));
    float* h1buf   = (float*)(ws + alloc(2 * H_ * B_ * 4));
    float* h1bb    = (float*)(ws + alloc(2 * H_ * B_ * 4));
    float* ctxT    = (float*)(ws + alloc(H_ * B_ * 4));
    float* ctxb    = (float*)(ws + alloc(H_ * B_ * 4));
    float* energyT = (float*)(ws + alloc(B_ * T_ * 4));
    float* vbuf    = (float*)(ws + alloc(B_ * T_ * 4));
    float* cdb     = (float*)(ws + alloc(B_ * M_ * 4));
    float* logit   = (float*)(ws + alloc(B_ * 64 * 4));
    int* colZero   = (int*)(ws + alloc(1024 * 4));
    int* bar       = (int*)(ws + alloc(2048 * 4));
    size_t baseNeed = off;
    size_t lbfBytes = (size_t)B_ * T_ * D_ * 2;
    int useBf = (baseNeed + lbfBytes + 256 <= ws_size) ? 1 : 0;
    unsigned short* Lbf = (unsigned short*)(ws + (useBf ? alloc(lbfBytes) : 0));
    (void)useBf;  // ws is ~141 MB minimum per harness; bf16 listener always fits

    hipMemsetAsync(bar, 0, 2048 * 4, stream);
    k_gemm<<<4096, 256, 0, stream>>>(Lf, psiw, psib, clT);
    k_conv<<<2048, 256, 0, stream>>>(Lf, Lbf, (B_ * T_ * D_) / 4);
    k_mega<<<NBLK, 256, 0, stream>>>(Lbf, Lf, gt,
                                     phiw, phib, wih0, whh0, bih0, bhh0,
                                     wih1, whh1, bih1, bhh1, charw, charb,
                                     clT, gtT, h0buf, h1buf, h1bb,
                                     ctxT, ctxb, energyT, vbuf,
                                     cdb, logit, colZero, bar, preds, atts);
}